// Round 8
// baseline (62.303 us; speedup 1.0000x reference)
//
#include <hip/hip_runtime.h>
#include <math.h>

// CircleLoss via bf16 MFMA:
//   prep:   normalize rows f32 -> bf16 (ws)
//   main:   tile sim = Fn @ Fn^T with mfma_f32_16x16x32_bf16, fused masked-exp
//           epilogue, per-(row, col-chunk) float2 partials (deterministic)
//   rowloss/final: log1p(p*n) per row, mean.

#define DIM 128
#define NCHUNK 32            // 16 colgroups * 2 waves-in-N
typedef short bf16x8 __attribute__((ext_vector_type(8)));
typedef float f32x4 __attribute__((ext_vector_type(4)));

#if __has_builtin(__builtin_amdgcn_exp2f)
#define EXP2F __builtin_amdgcn_exp2f
#else
#define EXP2F exp2f
#endif

__device__ __forceinline__ unsigned short f2bf(float f) {
    unsigned int b = __float_as_uint(f);
    unsigned int r = (b + 0x7FFFu + ((b >> 16) & 1u)) >> 16;   // RN-even
    return (unsigned short)r;
}

// ---------------- Kernel 1: normalize + quantize ----------------
__global__ void prep_kernel(const float* __restrict__ feats,
                            unsigned int* __restrict__ featsN, int B) {
    int wave = (blockIdx.x * blockDim.x + threadIdx.x) >> 6;
    int lane = threadIdx.x & 63;
    if (wave >= B) return;
    const float2* rp = (const float2*)(feats + (size_t)wave * DIM);
    float2 v = rp[lane];
    float s = v.x * v.x + v.y * v.y;
#pragma unroll
    for (int off = 32; off; off >>= 1) s += __shfl_xor(s, off);
    float inv = rsqrtf(s);
    unsigned int pack = (unsigned int)f2bf(v.x * inv) |
                        ((unsigned int)f2bf(v.y * inv) << 16);
    featsN[(size_t)wave * 64 + lane] = pack;
}

// ---------------- Kernel 2: fused MFMA sim + masked exp ----------------
// grid: (16 colgroups, 64 rowtiles), 256 threads (4 waves, 2x2 of 64x64).
__global__ __launch_bounds__(256, 2) void circle_main_kernel(
    const unsigned short* __restrict__ featsN, const int* __restrict__ labels,
    float2* __restrict__ partial, int B) {
    __shared__ unsigned char smem[65536] __attribute__((aligned(16)));
    unsigned char* Al = smem;            // 32KB: A tile [128][128] bf16, swizzled
    unsigned char* Bl = smem + 32768;    // 32KB: B subtile, swizzled

    const int tid = threadIdx.x;
    const int lane = tid & 63;
    const int wv = tid >> 6;             // 0..3
    const int wr = wv >> 1, wc = wv & 1; // wave row/col within 128x128
    const int lg = lane >> 4;            // lane group 0..3
    const int l15 = lane & 15;

    const int cg = blockIdx.x;           // col group: cols [cg*512, cg*512+512)
    const int rt = blockIdx.y;           // row tile:  rows [rt*128, rt*128+128)
    const int rowbase = rt * 128 + wr * 64;
    const int chunk = cg * 2 + wc;

    // ---- stage A tile (swizzled) ----
    {
        const int r0 = tid >> 4, c = tid & 15;
#pragma unroll
        for (int it = 0; it < 8; ++it) {
            int row = it * 16 + r0;
            int4 v = *(const int4*)(featsN + ((size_t)(rt * 128 + row) * DIM) + c * 8);
            *(int4*)(Al + row * 256 + ((c * 16) ^ ((row & 7) << 4))) = v;
        }
    }

    // row labels (fixed per block)
    int lr[4][4];
#pragma unroll
    for (int m = 0; m < 4; ++m)
#pragma unroll
        for (int r = 0; r < 4; ++r)
            lr[m][r] = labels[rowbase + m * 16 + lg * 4 + r];

    bf16x8 afrag[4][4];
    float accP[4][4], accN[4][4];
#pragma unroll
    for (int m = 0; m < 4; ++m)
#pragma unroll
        for (int r = 0; r < 4; ++r) { accP[m][r] = 0.f; accN[m][r] = 0.f; }

    const float S2 = 46.16624130844683f;  // 32 * log2(e)

    for (int s = 0; s < 4; ++s) {
        __syncthreads();   // A staged (s=0) / previous B reads done (s>0)
        // ---- stage B subtile (swizzled) ----
        {
            const int r0 = tid >> 4, c = tid & 15;
            const size_t gbase = (size_t)(cg * 512 + s * 128) * DIM;
#pragma unroll
            for (int it = 0; it < 8; ++it) {
                int row = it * 16 + r0;
                int4 v = *(const int4*)(featsN + gbase + (size_t)row * DIM + c * 8);
                *(int4*)(Bl + row * 256 + ((c * 16) ^ ((row & 7) << 4))) = v;
            }
        }
        __syncthreads();

        if (s == 0) {
            // A fragments -> registers, kept for all subtiles
#pragma unroll
            for (int m = 0; m < 4; ++m)
#pragma unroll
                for (int kk = 0; kk < 4; ++kk) {
                    int row = wr * 64 + m * 16 + l15;
                    int off = row * 256 + ((kk * 64 + lg * 16) ^ ((row & 7) << 4));
                    afrag[m][kk] = __builtin_bit_cast(bf16x8, *(const int4*)(Al + off));
                }
        }

        // ---- MFMA: 64 per wave ----
        f32x4 acc[4][4];
#pragma unroll
        for (int m = 0; m < 4; ++m)
#pragma unroll
            for (int n = 0; n < 4; ++n) acc[m][n] = (f32x4){0.f, 0.f, 0.f, 0.f};
#pragma unroll
        for (int kk = 0; kk < 4; ++kk) {
            bf16x8 bfrag[4];
#pragma unroll
            for (int n = 0; n < 4; ++n) {
                int row = wc * 64 + n * 16 + l15;
                int off = row * 256 + ((kk * 64 + lg * 16) ^ ((row & 7) << 4));
                bfrag[n] = __builtin_bit_cast(bf16x8, *(const int4*)(Bl + off));
            }
#pragma unroll
            for (int m = 0; m < 4; ++m)
#pragma unroll
                for (int n = 0; n < 4; ++n)
                    acc[m][n] = __builtin_amdgcn_mfma_f32_16x16x32_bf16(
                        afrag[m][kk], bfrag[n], acc[m][n], 0, 0, 0);
        }

        // ---- epilogue: masked exp, accumulate per-lane row partials ----
        const int colbase = cg * 512 + s * 128 + wc * 64;
        int lc[4];
#pragma unroll
        for (int n = 0; n < 4; ++n) lc[n] = labels[colbase + n * 16 + l15];

#pragma unroll
        for (int m = 0; m < 4; ++m) {
#pragma unroll
            for (int r = 0; r < 4; ++r) {
                const int grow = rowbase + m * 16 + lg * 4 + r;
                const int lrow = lr[m][r];
                float pAcc = 0.f, nAcc = 0.f;
#pragma unroll
                for (int n = 0; n < 4; ++n) {
                    float sim = acc[m][n][r];
                    bool same = (lrow == lc[n]);
                    int gcol = colbase + n * 16 + l15;
                    bool self = (grow == gcol);
                    float ep = fmaxf(1.25f - sim, 0.f) * (sim - 0.75f);
                    float en = fmaxf(sim + 0.25f, 0.f) * (sim - 0.25f);
                    float e2 = (same ? -ep : en) * S2;
                    float v = EXP2F(e2);
                    nAcc += same ? 0.f : v;
                    pAcc += (same && !self) ? v : 0.f;
                }
                accP[m][r] += pAcc;
                accN[m][r] += nAcc;
            }
        }
    }

    // ---- reduce across the 16 lanes of each group, write partials ----
#pragma unroll
    for (int m = 0; m < 4; ++m) {
#pragma unroll
        for (int r = 0; r < 4; ++r) {
            float p = accP[m][r], n_ = accN[m][r];
#pragma unroll
            for (int off = 1; off < 16; off <<= 1) {
                p += __shfl_xor(p, off);
                n_ += __shfl_xor(n_, off);
            }
            if (l15 == 0) {
                int row = rowbase + m * 16 + lg * 4 + r;
                partial[(size_t)row * NCHUNK + chunk] = make_float2(p, n_);
            }
        }
    }
}

// ---------------- Kernel 3: per-row log1p(p*n), block sums ----------------
__global__ void rowloss_kernel(const float2* __restrict__ partial,
                               double* __restrict__ blocksum, int B) {
    __shared__ double sdata[256];
    int tid = threadIdx.x;
    int row = blockIdx.x * 256 + tid;
    const float4* pp = (const float4*)(partial + (size_t)row * NCHUNK);
    float p = 0.f, n = 0.f;
#pragma unroll
    for (int c = 0; c < NCHUNK / 2; ++c) {
        float4 v = pp[c];
        p += v.x + v.z;
        n += v.y + v.w;
    }
    sdata[tid] = log1p((double)p * (double)n);
    __syncthreads();
    for (int s = 128; s; s >>= 1) {
        if (tid < s) sdata[tid] += sdata[tid + s];
        __syncthreads();
    }
    if (tid == 0) blocksum[blockIdx.x] = sdata[0];
}

__global__ void final_kernel(const double* __restrict__ blocksum,
                             float* __restrict__ out, int nblk, int B) {
    __shared__ double sdata[64];
    int tid = threadIdx.x;
    sdata[tid] = (tid < nblk) ? blocksum[tid] : 0.0;
    __syncthreads();
    for (int s = 32; s; s >>= 1) {
        if (tid < s) sdata[tid] += sdata[tid + s];
        __syncthreads();
    }
    if (tid == 0) out[0] = (float)(sdata[0] / (double)B);
}

extern "C" void kernel_launch(void* const* d_in, const int* in_sizes, int n_in,
                              void* d_out, int out_size, void* d_ws, size_t ws_size,
                              hipStream_t stream) {
    const float* feats = (const float*)d_in[0];
    const int* labels = (const int*)d_in[1];
    float* out = (float*)d_out;
    int B = in_sizes[1];  // 8192

    // ws: featsN bf16 [B][128] (2MB) | partial float2 [B][NCHUNK] (2MB) | blocksum
    unsigned int* featsN = (unsigned int*)d_ws;
    size_t off1 = ((size_t)B * DIM * 2 + 255) & ~(size_t)255;
    float2* partial = (float2*)((char*)d_ws + off1);
    size_t off2 = off1 + (((size_t)B * NCHUNK * 8 + 255) & ~(size_t)255);
    double* blocksum = (double*)((char*)d_ws + off2);

    prep_kernel<<<B / 4, 256, 0, stream>>>(feats, featsN, B);

    dim3 grid(16, B / 128);
    circle_main_kernel<<<grid, 256, 0, stream>>>((const unsigned short*)featsN,
                                                 labels, partial, B);

    int nblk = B / 256;
    rowloss_kernel<<<nblk, 256, 0, stream>>>(partial, blocksum, B);
    final_kernel<<<1, 64, 0, stream>>>(blocksum, out, nblk, B);
}

// Round 9
// 57.200 us; speedup vs baseline: 1.0892x; 1.0892x over previous
//
#include <hip/hip_runtime.h>
#include <math.h>

// CircleLoss via bf16 MFMA — R2/R8-validated structure.
// R9 delta (ONLY change vs R8): epilogue inner arithmetic uses the u-form:
//   u = same ? 1.25-sim : sim+0.25;  e2 = relu(u) * (S2*u - S2/2)
// which is pointwise identical to the ep/en form (both = S2*relu(u)*(u-0.5)).
// Everything else byte-identical to the passing R8 kernel.

#define DIM 128
#define NCHUNK 32            // 16 colgroups * 2 waves-in-N
typedef short bf16x8 __attribute__((ext_vector_type(8)));
typedef float f32x4 __attribute__((ext_vector_type(4)));

#if __has_builtin(__builtin_amdgcn_exp2f)
#define EXP2F __builtin_amdgcn_exp2f
#else
#define EXP2F exp2f
#endif

__device__ __forceinline__ unsigned short f2bf(float f) {
    unsigned int b = __float_as_uint(f);
    unsigned int r = (b + 0x7FFFu + ((b >> 16) & 1u)) >> 16;   // RN-even
    return (unsigned short)r;
}

// ---------------- Kernel 1: normalize + quantize ----------------
__global__ void prep_kernel(const float* __restrict__ feats,
                            unsigned int* __restrict__ featsN, int B) {
    int wave = (blockIdx.x * blockDim.x + threadIdx.x) >> 6;
    int lane = threadIdx.x & 63;
    if (wave >= B) return;
    const float2* rp = (const float2*)(feats + (size_t)wave * DIM);
    float2 v = rp[lane];
    float s = v.x * v.x + v.y * v.y;
#pragma unroll
    for (int off = 32; off; off >>= 1) s += __shfl_xor(s, off);
    float inv = rsqrtf(s);
    unsigned int pack = (unsigned int)f2bf(v.x * inv) |
                        ((unsigned int)f2bf(v.y * inv) << 16);
    featsN[(size_t)wave * 64 + lane] = pack;
}

// ---------------- Kernel 2: fused MFMA sim + masked exp ----------------
// grid: (16 colgroups, 64 rowtiles), 256 threads (4 waves, 2x2 of 64x64).
__global__ __launch_bounds__(256, 2) void circle_main_kernel(
    const unsigned short* __restrict__ featsN, const int* __restrict__ labels,
    float2* __restrict__ partial, int B) {
    __shared__ unsigned char smem[65536] __attribute__((aligned(16)));
    unsigned char* Al = smem;            // 32KB: A tile [128][128] bf16, swizzled
    unsigned char* Bl = smem + 32768;    // 32KB: B subtile, swizzled

    const int tid = threadIdx.x;
    const int lane = tid & 63;
    const int wv = tid >> 6;             // 0..3
    const int wr = wv >> 1, wc = wv & 1; // wave row/col within 128x128
    const int lg = lane >> 4;            // lane group 0..3
    const int l15 = lane & 15;

    const int cg = blockIdx.x;           // col group: cols [cg*512, cg*512+512)
    const int rt = blockIdx.y;           // row tile:  rows [rt*128, rt*128+128)
    const int rowbase = rt * 128 + wr * 64;
    const int chunk = cg * 2 + wc;

    // ---- stage A tile (swizzled) ----
    {
        const int r0 = tid >> 4, c = tid & 15;
#pragma unroll
        for (int it = 0; it < 8; ++it) {
            int row = it * 16 + r0;
            int4 v = *(const int4*)(featsN + ((size_t)(rt * 128 + row) * DIM) + c * 8);
            *(int4*)(Al + row * 256 + ((c * 16) ^ ((row & 7) << 4))) = v;
        }
    }

    // row labels (fixed per block)
    int lr[4][4];
#pragma unroll
    for (int m = 0; m < 4; ++m)
#pragma unroll
        for (int r = 0; r < 4; ++r)
            lr[m][r] = labels[rowbase + m * 16 + lg * 4 + r];

    bf16x8 afrag[4][4];
    float accP[4][4], accN[4][4];
#pragma unroll
    for (int m = 0; m < 4; ++m)
#pragma unroll
        for (int r = 0; r < 4; ++r) { accP[m][r] = 0.f; accN[m][r] = 0.f; }

    const float S2 = 46.16624130844683f;   // 32 * log2(e)
    const float C2 = -23.083120654223414f; // -0.5 * S2

    for (int s = 0; s < 4; ++s) {
        __syncthreads();   // A staged (s=0) / previous B reads done (s>0)
        // ---- stage B subtile (swizzled) ----
        {
            const int r0 = tid >> 4, c = tid & 15;
            const size_t gbase = (size_t)(cg * 512 + s * 128) * DIM;
#pragma unroll
            for (int it = 0; it < 8; ++it) {
                int row = it * 16 + r0;
                int4 v = *(const int4*)(featsN + gbase + (size_t)row * DIM + c * 8);
                *(int4*)(Bl + row * 256 + ((c * 16) ^ ((row & 7) << 4))) = v;
            }
        }
        __syncthreads();

        if (s == 0) {
            // A fragments -> registers, kept for all subtiles
#pragma unroll
            for (int m = 0; m < 4; ++m)
#pragma unroll
                for (int kk = 0; kk < 4; ++kk) {
                    int row = wr * 64 + m * 16 + l15;
                    int off = row * 256 + ((kk * 64 + lg * 16) ^ ((row & 7) << 4));
                    afrag[m][kk] = __builtin_bit_cast(bf16x8, *(const int4*)(Al + off));
                }
        }

        // ---- MFMA: 64 per wave ----
        f32x4 acc[4][4];
#pragma unroll
        for (int m = 0; m < 4; ++m)
#pragma unroll
            for (int n = 0; n < 4; ++n) acc[m][n] = (f32x4){0.f, 0.f, 0.f, 0.f};
#pragma unroll
        for (int kk = 0; kk < 4; ++kk) {
            bf16x8 bfrag[4];
#pragma unroll
            for (int n = 0; n < 4; ++n) {
                int row = wc * 64 + n * 16 + l15;
                int off = row * 256 + ((kk * 64 + lg * 16) ^ ((row & 7) << 4));
                bfrag[n] = __builtin_bit_cast(bf16x8, *(const int4*)(Bl + off));
            }
#pragma unroll
            for (int m = 0; m < 4; ++m)
#pragma unroll
                for (int n = 0; n < 4; ++n)
                    acc[m][n] = __builtin_amdgcn_mfma_f32_16x16x32_bf16(
                        afrag[m][kk], bfrag[n], acc[m][n], 0, 0, 0);
        }

        // ---- epilogue: masked exp (u-form), accumulate per-lane row partials ----
        const int colbase = cg * 512 + s * 128 + wc * 64;
        int lc[4];
#pragma unroll
        for (int n = 0; n < 4; ++n) lc[n] = labels[colbase + n * 16 + l15];

#pragma unroll
        for (int m = 0; m < 4; ++m) {
#pragma unroll
            for (int r = 0; r < 4; ++r) {
                const int grow = rowbase + m * 16 + lg * 4 + r;
                const int lrow = lr[m][r];
                float pAcc = 0.f, nAcc = 0.f;
#pragma unroll
                for (int n = 0; n < 4; ++n) {
                    float sim = acc[m][n][r];
                    bool same = (lrow == lc[n]);
                    int gcol = colbase + n * 16 + l15;
                    bool self = (grow == gcol);
                    float u = same ? (1.25f - sim) : (sim + 0.25f);
                    float e2 = fmaxf(u, 0.f) * fmaf(S2, u, C2);
                    float v = EXP2F(e2);
                    nAcc += same ? 0.f : v;
                    pAcc += (same && !self) ? v : 0.f;
                }
                accP[m][r] += pAcc;
                accN[m][r] += nAcc;
            }
        }
    }

    // ---- reduce across the 16 lanes of each group, write partials ----
#pragma unroll
    for (int m = 0; m < 4; ++m) {
#pragma unroll
        for (int r = 0; r < 4; ++r) {
            float p = accP[m][r], n_ = accN[m][r];
#pragma unroll
            for (int off = 1; off < 16; off <<= 1) {
                p += __shfl_xor(p, off);
                n_ += __shfl_xor(n_, off);
            }
            if (l15 == 0) {
                int row = rowbase + m * 16 + lg * 4 + r;
                partial[(size_t)row * NCHUNK + chunk] = make_float2(p, n_);
            }
        }
    }
}

// ---------------- Kernel 3: per-row log1p(p*n), block sums ----------------
__global__ void rowloss_kernel(const float2* __restrict__ partial,
                               double* __restrict__ blocksum, int B) {
    __shared__ double sdata[256];
    int tid = threadIdx.x;
    int row = blockIdx.x * 256 + tid;
    const float4* pp = (const float4*)(partial + (size_t)row * NCHUNK);
    float p = 0.f, n = 0.f;
#pragma unroll
    for (int c = 0; c < NCHUNK / 2; ++c) {
        float4 v = pp[c];
        p += v.x + v.z;
        n += v.y + v.w;
    }
    sdata[tid] = log1p((double)p * (double)n);
    __syncthreads();
    for (int s = 128; s; s >>= 1) {
        if (tid < s) sdata[tid] += sdata[tid + s];
        __syncthreads();
    }
    if (tid == 0) blocksum[blockIdx.x] = sdata[0];
}

__global__ void final_kernel(const double* __restrict__ blocksum,
                             float* __restrict__ out, int nblk, int B) {
    __shared__ double sdata[64];
    int tid = threadIdx.x;
    sdata[tid] = (tid < nblk) ? blocksum[tid] : 0.0;
    __syncthreads();
    for (int s = 32; s; s >>= 1) {
        if (tid < s) sdata[tid] += sdata[tid + s];
        __syncthreads();
    }
    if (tid == 0) out[0] = (float)(sdata[0] / (double)B);
}

extern "C" void kernel_launch(void* const* d_in, const int* in_sizes, int n_in,
                              void* d_out, int out_size, void* d_ws, size_t ws_size,
                              hipStream_t stream) {
    const float* feats = (const float*)d_in[0];
    const int* labels = (const int*)d_in[1];
    float* out = (float*)d_out;
    int B = in_sizes[1];  // 8192

    // ws: featsN bf16 [B][128] (2MB) | partial float2 [B][NCHUNK] (2MB) | blocksum
    unsigned int* featsN = (unsigned int*)d_ws;
    size_t off1 = ((size_t)B * DIM * 2 + 255) & ~(size_t)255;
    float2* partial = (float2*)((char*)d_ws + off1);
    size_t off2 = off1 + (((size_t)B * NCHUNK * 8 + 255) & ~(size_t)255);
    double* blocksum = (double*)((char*)d_ws + off2);

    prep_kernel<<<B / 4, 256, 0, stream>>>(feats, featsN, B);

    dim3 grid(16, B / 128);
    circle_main_kernel<<<grid, 256, 0, stream>>>((const unsigned short*)featsN,
                                                 labels, partial, B);

    int nblk = B / 256;
    rowloss_kernel<<<nblk, 256, 0, stream>>>(partial, blocksum, B);
    final_kernel<<<1, 64, 0, stream>>>(blocksum, out, nblk, B);
}